// Round 1
// baseline (567.993 us; speedup 1.0000x reference)
//
#include <hip/hip_runtime.h>

// GCN autoencoder: N=50000 nodes, E=800000 edges, 128 -> 16 -> 128.
// Round 0: correctness-first, atomic-scatter formulation.

#define N_NODES 50000
#define N_EDGES 800000
#define D_IN    128
#define D_H     16

// ---- stage 1: degree (on dst, per PyG gcn_norm) ----
__global__ void deg_kernel(const int* __restrict__ dst, float* __restrict__ deg) {
    int e = blockIdx.x * blockDim.x + threadIdx.x;
    if (e < N_EDGES) atomicAdd(&deg[dst[e]], 1.0f);
}

__global__ void dinv_kernel(const float* __restrict__ deg, float* __restrict__ dinv) {
    int i = blockIdx.x * blockDim.x + threadIdx.x;
    if (i < N_NODES) dinv[i] = rsqrtf(deg[i] + 1.0f);  // +1 = self loop
}

// ---- stage 2: h1 = x @ W1  [N,128]@[128,16] ----
__global__ void h1_kernel(const float* __restrict__ x, const float* __restrict__ W1,
                          float* __restrict__ h1) {
    int idx = blockIdx.x * blockDim.x + threadIdx.x;
    if (idx >= N_NODES * D_H) return;
    int row = idx >> 4;       // /16
    int col = idx & 15;
    const float* xr = x + row * D_IN;
    float acc = 0.0f;
    #pragma unroll
    for (int k = 0; k < D_IN; ++k) acc += xr[k] * W1[k * D_H + col];
    h1[idx] = acc;
}

// ---- stage 3: z = self-loop init + edge scatter (16-wide) ----
__global__ void z_init_kernel(const float* __restrict__ h1, const float* __restrict__ dinv,
                              float* __restrict__ z) {
    int idx = blockIdx.x * blockDim.x + threadIdx.x;
    if (idx >= N_NODES * D_H) return;
    int row = idx >> 4;
    float di = dinv[row];
    z[idx] = h1[idx] * di * di;
}

__global__ void z_scatter_kernel(const int* __restrict__ src, const int* __restrict__ dst,
                                 const float* __restrict__ dinv,
                                 const float* __restrict__ h1, float* __restrict__ z) {
    long long idx = (long long)blockIdx.x * blockDim.x + threadIdx.x;
    if (idx >= (long long)N_EDGES * D_H) return;
    int e = (int)(idx >> 4);
    int c = (int)(idx & 15);
    int s = src[e], d = dst[e];
    float norm = dinv[s] * dinv[d];
    atomicAdd(&z[d * D_H + c], h1[s * D_H + c] * norm);
}

// ---- stage 4: h2 = (z + b1) @ W2  [N,16]@[16,128] ----
__global__ void h2_kernel(const float* __restrict__ z, const float* __restrict__ b1,
                          const float* __restrict__ W2, float* __restrict__ h2) {
    int row = blockIdx.x;      // one block per node, 128 threads = output cols
    int j = threadIdx.x;
    float acc = 0.0f;
    #pragma unroll
    for (int c = 0; c < D_H; ++c) {
        acc += (z[row * D_H + c] + b1[c]) * W2[c * D_IN + j];
    }
    h2[row * D_IN + j] = acc;
}

// ---- stage 5: out = self-loop init + bias, then edge scatter (128-wide) ----
__global__ void out_init_kernel(const float* __restrict__ h2, const float* __restrict__ dinv,
                                const float* __restrict__ b2, float* __restrict__ out) {
    int idx = blockIdx.x * blockDim.x + threadIdx.x;
    if (idx >= N_NODES * D_IN) return;
    int row = idx >> 7;
    int j = idx & 127;
    float di = dinv[row];
    out[idx] = h2[idx] * di * di + b2[j];
}

__global__ void out_scatter_kernel(const int* __restrict__ src, const int* __restrict__ dst,
                                   const float* __restrict__ dinv,
                                   const float* __restrict__ h2, float* __restrict__ out) {
    long long idx = (long long)blockIdx.x * blockDim.x + threadIdx.x;
    if (idx >= (long long)N_EDGES * D_IN) return;
    int e = (int)(idx >> 7);
    int j = (int)(idx & 127);
    int s = src[e], d = dst[e];
    float norm = dinv[s] * dinv[d];
    atomicAdd(&out[d * D_IN + j], h2[s * D_IN + j] * norm);
}

extern "C" void kernel_launch(void* const* d_in, const int* in_sizes, int n_in,
                              void* d_out, int out_size, void* d_ws, size_t ws_size,
                              hipStream_t stream) {
    const float* x  = (const float*)d_in[0];
    const int*   ei = (const int*)d_in[1];   // [2, E] flattened: src then dst
    const float* W1 = (const float*)d_in[2];
    const float* b1 = (const float*)d_in[3];
    const float* W2 = (const float*)d_in[4];
    const float* b2 = (const float*)d_in[5];
    float* out = (float*)d_out;

    const int* src = ei;
    const int* dst = ei + N_EDGES;

    // workspace layout (floats): deg[N] | dinv[N] | h1[N*16] | z[N*16] | h2[N*128]
    float* ws   = (float*)d_ws;
    float* deg  = ws;
    float* dinv = ws + N_NODES;
    float* h1   = ws + 2 * N_NODES;
    float* z    = h1 + N_NODES * D_H;
    float* h2   = z + N_NODES * D_H;

    hipMemsetAsync(deg, 0, N_NODES * sizeof(float), stream);

    deg_kernel<<<(N_EDGES + 255) / 256, 256, 0, stream>>>(dst, deg);
    dinv_kernel<<<(N_NODES + 255) / 256, 256, 0, stream>>>(deg, dinv);

    h1_kernel<<<(N_NODES * D_H + 255) / 256, 256, 0, stream>>>(x, W1, h1);

    z_init_kernel<<<(N_NODES * D_H + 255) / 256, 256, 0, stream>>>(h1, dinv, z);
    {
        long long total = (long long)N_EDGES * D_H;
        z_scatter_kernel<<<(int)((total + 255) / 256), 256, 0, stream>>>(src, dst, dinv, h1, z);
    }

    h2_kernel<<<N_NODES, D_IN, 0, stream>>>(z, b1, W2, h2);

    out_init_kernel<<<(N_NODES * D_IN + 255) / 256, 256, 0, stream>>>(h2, dinv, b2, out);
    {
        long long total = (long long)N_EDGES * D_IN;
        out_scatter_kernel<<<(int)((total + 255) / 256), 256, 0, stream>>>(src, dst, dinv, h2, out);
    }
}

// Round 2
// 491.726 us; speedup vs baseline: 1.1551x; 1.1551x over previous
//
#include <hip/hip_runtime.h>

// GCN autoencoder: N=50000, E=800000, 128 -> 16 -> 128.
// Round 2: exploit linearity — aggregate z (16-wide) in the decoder instead of
// h2 (128-wide): out = (S norm*z[s] + z*dinv^2) @ W2 + b2. 8x less atomic traffic,
// accumulator (3.2 MB) is L2-resident.

#define N_NODES 50000
#define N_EDGES 800000
#define D_IN    128
#define D_H     16

// ---- degree on dst ----
__global__ void deg_kernel(const int* __restrict__ dst, float* __restrict__ deg) {
    int e = blockIdx.x * blockDim.x + threadIdx.x;
    if (e < N_EDGES) atomicAdd(&deg[dst[e]], 1.0f);
}

__global__ void dinv_kernel(const float* __restrict__ deg, float* __restrict__ dinv) {
    int i = blockIdx.x * blockDim.x + threadIdx.x;
    if (i < N_NODES) dinv[i] = rsqrtf(deg[i] + 1.0f);
}

// ---- h1 = x @ W1, and z initialized to self-loop term h1*dinv^2 ----
__global__ void h1_kernel(const float* __restrict__ x, const float* __restrict__ W1,
                          const float* __restrict__ dinv,
                          float* __restrict__ h1, float* __restrict__ z) {
    __shared__ float w1s[D_IN * D_H];  // 8 KB
    int tid = threadIdx.x;
    #pragma unroll
    for (int i = tid; i < D_IN * D_H; i += 256) w1s[i] = W1[i];
    __syncthreads();

    int idx = blockIdx.x * 256 + tid;
    if (idx >= N_NODES * D_H) return;
    int row = idx >> 4;
    int col = idx & 15;
    const float4* xr = (const float4*)(x + row * D_IN);
    float acc = 0.0f;
    #pragma unroll
    for (int k4 = 0; k4 < D_IN / 4; ++k4) {
        float4 v = xr[k4];
        acc += v.x * w1s[(k4 * 4 + 0) * D_H + col];
        acc += v.y * w1s[(k4 * 4 + 1) * D_H + col];
        acc += v.z * w1s[(k4 * 4 + 2) * D_H + col];
        acc += v.w * w1s[(k4 * 4 + 3) * D_H + col];
    }
    h1[idx] = acc;
    float di = dinv[row];
    z[idx] = acc * di * di;
}

// ---- z += scatter(norm * h1[src] -> dst), 4 threads/edge, float4 gathers ----
__global__ void z_scatter_kernel(const int* __restrict__ src, const int* __restrict__ dst,
                                 const float* __restrict__ dinv,
                                 const float* __restrict__ h1, float* __restrict__ z) {
    int idx = blockIdx.x * blockDim.x + threadIdx.x;
    if (idx >= N_EDGES * 4) return;
    int e = idx >> 2;
    int g = (idx & 3) * 4;
    int s = src[e], d = dst[e];
    float norm = dinv[s] * dinv[d];
    float4 v = *(const float4*)(h1 + s * D_H + g);
    float* zp = z + d * D_H + g;
    atomicAdd(zp + 0, v.x * norm);
    atomicAdd(zp + 1, v.y * norm);
    atomicAdd(zp + 2, v.z * norm);
    atomicAdd(zp + 3, v.w * norm);
}

// ---- z += b1 (finalize encoder); agg2 initialized to z*dinv^2 (decoder self-loop) ----
__global__ void finish_z_kernel(const float* __restrict__ b1, const float* __restrict__ dinv,
                                float* __restrict__ z, float* __restrict__ agg2) {
    int idx = blockIdx.x * blockDim.x + threadIdx.x;   // over N*4 float4 groups
    if (idx >= N_NODES * 4) return;
    int row = idx >> 2;
    int g = idx & 3;
    float4 bv = ((const float4*)b1)[g];
    float4 zv = ((float4*)z)[idx];
    zv.x += bv.x; zv.y += bv.y; zv.z += bv.z; zv.w += bv.w;
    ((float4*)z)[idx] = zv;
    float di = dinv[row];
    float d2 = di * di;
    float4 av = make_float4(zv.x * d2, zv.y * d2, zv.z * d2, zv.w * d2);
    ((float4*)agg2)[idx] = av;
}

// ---- agg2 += scatter(norm * z[src] -> dst) ----
__global__ void agg2_scatter_kernel(const int* __restrict__ src, const int* __restrict__ dst,
                                    const float* __restrict__ dinv,
                                    const float* __restrict__ z, float* __restrict__ agg2) {
    int idx = blockIdx.x * blockDim.x + threadIdx.x;
    if (idx >= N_EDGES * 4) return;
    int e = idx >> 2;
    int g = (idx & 3) * 4;
    int s = src[e], d = dst[e];
    float norm = dinv[s] * dinv[d];
    float4 v = *(const float4*)(z + s * D_H + g);
    float* ap = agg2 + d * D_H + g;
    atomicAdd(ap + 0, v.x * norm);
    atomicAdd(ap + 1, v.y * norm);
    atomicAdd(ap + 2, v.z * norm);
    atomicAdd(ap + 3, v.w * norm);
}

// ---- out = agg2 @ W2 + b2 ----
__global__ void out_kernel(const float* __restrict__ agg2, const float* __restrict__ W2,
                           const float* __restrict__ b2, float* __restrict__ out) {
    int idx = blockIdx.x * blockDim.x + threadIdx.x;   // over N*32 float4 groups
    if (idx >= N_NODES * (D_IN / 4)) return;
    int row = idx >> 5;
    int j4 = idx & 31;
    const float* ar = agg2 + row * D_H;
    float4 acc = ((const float4*)b2)[j4];
    #pragma unroll
    for (int c = 0; c < D_H; ++c) {
        float a = ar[c];
        float4 w = ((const float4*)(W2 + c * D_IN))[j4];
        acc.x += a * w.x; acc.y += a * w.y; acc.z += a * w.z; acc.w += a * w.w;
    }
    ((float4*)(out))[idx] = acc;
}

extern "C" void kernel_launch(void* const* d_in, const int* in_sizes, int n_in,
                              void* d_out, int out_size, void* d_ws, size_t ws_size,
                              hipStream_t stream) {
    const float* x  = (const float*)d_in[0];
    const int*   ei = (const int*)d_in[1];   // [2, E]: src then dst
    const float* W1 = (const float*)d_in[2];
    const float* b1 = (const float*)d_in[3];
    const float* W2 = (const float*)d_in[4];
    const float* b2 = (const float*)d_in[5];
    float* out = (float*)d_out;

    const int* src = ei;
    const int* dst = ei + N_EDGES;

    // ws floats: deg[N] | dinv[N] | h1[N*16] | z[N*16] | agg2[N*16]  (10 MB)
    float* ws   = (float*)d_ws;
    float* deg  = ws;
    float* dinv = ws + N_NODES;
    float* h1   = ws + 2 * N_NODES;
    float* z    = h1 + N_NODES * D_H;
    float* agg2 = z + N_NODES * D_H;

    hipMemsetAsync(deg, 0, N_NODES * sizeof(float), stream);

    deg_kernel<<<(N_EDGES + 255) / 256, 256, 0, stream>>>(dst, deg);
    dinv_kernel<<<(N_NODES + 255) / 256, 256, 0, stream>>>(deg, dinv);

    h1_kernel<<<(N_NODES * D_H + 255) / 256, 256, 0, stream>>>(x, W1, dinv, h1, z);

    z_scatter_kernel<<<(N_EDGES * 4 + 255) / 256, 256, 0, stream>>>(src, dst, dinv, h1, z);

    finish_z_kernel<<<(N_NODES * 4 + 255) / 256, 256, 0, stream>>>(b1, dinv, z, agg2);

    agg2_scatter_kernel<<<(N_EDGES * 4 + 255) / 256, 256, 0, stream>>>(src, dst, dinv, z, agg2);

    out_kernel<<<(N_NODES * 32 + 255) / 256, 256, 0, stream>>>(agg2, W2, b2, out);
}

// Round 4
// 259.784 us; speedup vs baseline: 2.1864x; 1.8928x over previous
//
#include <hip/hip_runtime.h>

// GCN autoencoder: N=50000, E=800000, 128 -> 16 -> 128.
// Round 4 (= Round 3 resubmit after infra flake): on-device CSR build +
// gather-reduce. Device fp32 atomics resolve at the memory-side coherence
// point (200 MB HBM writes per scatter, R2 rocprof) — gathers from
// L2-resident 3.2 MB feat arrays avoid that entirely.

#define N_NODES 50000
#define N_EDGES 800000
#define D_IN    128
#define D_H     16
#define SCAN_B  256
#define N_CHUNK ((N_NODES + SCAN_B - 1) / SCAN_B)   // 196

// ---- CSR build ----
__global__ void deg_int_kernel(const int* __restrict__ dst, int* __restrict__ degi) {
    int e = blockIdx.x * blockDim.x + threadIdx.x;
    if (e < N_EDGES) atomicAdd(&degi[dst[e]], 1);
}

__global__ void dinv_kernel(const int* __restrict__ degi, float* __restrict__ dinv) {
    int i = blockIdx.x * blockDim.x + threadIdx.x;
    if (i < N_NODES) dinv[i] = rsqrtf((float)degi[i] + 1.0f);  // +1 self loop
}

__global__ void scan_partial(const int* __restrict__ degi, int* __restrict__ part) {
    __shared__ int s[SCAN_B];
    int tid = threadIdx.x;
    int idx = blockIdx.x * SCAN_B + tid;
    s[tid] = idx < N_NODES ? degi[idx] : 0;
    __syncthreads();
    for (int off = 128; off > 0; off >>= 1) {
        if (tid < off) s[tid] += s[tid + off];
        __syncthreads();
    }
    if (tid == 0) part[blockIdx.x] = s[0];
}

__global__ void scan_spine(int* __restrict__ part, int* __restrict__ row_off) {
    __shared__ int s[SCAN_B];
    int tid = threadIdx.x;
    int v = tid < N_CHUNK ? part[tid] : 0;
    s[tid] = v;
    __syncthreads();
    for (int off = 1; off < SCAN_B; off <<= 1) {
        int t = tid >= off ? s[tid - off] : 0;
        __syncthreads();
        s[tid] += t;
        __syncthreads();
    }
    part[tid] = s[tid] - v;  // exclusive
    if (tid == 0) row_off[N_NODES] = N_EDGES;
}

__global__ void scan_final(const int* __restrict__ degi, const int* __restrict__ part,
                           int* __restrict__ row_off, int* __restrict__ cursor) {
    __shared__ int s[SCAN_B];
    int tid = threadIdx.x;
    int idx = blockIdx.x * SCAN_B + tid;
    int v = idx < N_NODES ? degi[idx] : 0;
    s[tid] = v;
    __syncthreads();
    for (int off = 1; off < SCAN_B; off <<= 1) {
        int t = tid >= off ? s[tid - off] : 0;
        __syncthreads();
        s[tid] += t;
        __syncthreads();
    }
    if (idx < N_NODES) {
        int o = part[blockIdx.x] + s[tid] - v;
        row_off[idx] = o;
        cursor[idx] = o;
    }
}

__global__ void fill_kernel(const int* __restrict__ src, const int* __restrict__ dst,
                            int* __restrict__ cursor, int* __restrict__ edge_src) {
    int e = blockIdx.x * blockDim.x + threadIdx.x;
    if (e < N_EDGES) {
        int d = dst[e];
        int p = atomicAdd(&cursor[d], 1);
        edge_src[p] = src[e];
    }
}

// ---- h1 = x @ W1 ----
__global__ void h1_kernel(const float* __restrict__ x, const float* __restrict__ W1,
                          float* __restrict__ h1) {
    __shared__ float w1s[D_IN * D_H];  // 8 KB
    int tid = threadIdx.x;
    for (int i = tid; i < D_IN * D_H; i += 256) w1s[i] = W1[i];
    __syncthreads();

    int idx = blockIdx.x * 256 + tid;
    if (idx >= N_NODES * D_H) return;
    int row = idx >> 4;
    int col = idx & 15;
    const float4* xr = (const float4*)(x + row * D_IN);
    float acc = 0.0f;
    #pragma unroll
    for (int k4 = 0; k4 < D_IN / 4; ++k4) {
        float4 v = xr[k4];
        acc += v.x * w1s[(k4 * 4 + 0) * D_H + col];
        acc += v.y * w1s[(k4 * 4 + 1) * D_H + col];
        acc += v.z * w1s[(k4 * 4 + 2) * D_H + col];
        acc += v.w * w1s[(k4 * 4 + 3) * D_H + col];
    }
    h1[idx] = acc;
}

// ---- CSR gather-aggregate: out[i,t] = dinv[i]^2*feat[i,t]
//      + sum_{p in [row_off[i],row_off[i+1])} dinv[s]*dinv[i]*feat[s,t]  (+ bias[t]) ----
// 16 lanes per node (one per channel), 16 nodes per 256-block.
__global__ void gather_kernel(const float* __restrict__ feat, const int* __restrict__ row_off,
                              const int* __restrict__ edge_src, const float* __restrict__ dinv,
                              const float* __restrict__ bias, float* __restrict__ outf) {
    int tid = threadIdx.x;
    int node = blockIdx.x * 16 + (tid >> 4);
    int t = tid & 15;
    if (node >= N_NODES) return;
    float di = dinv[node];
    float acc = feat[node * D_H + t] * di * di;
    int p0 = row_off[node], p1 = row_off[node + 1];
    for (int p = p0; p < p1; ++p) {
        int s = edge_src[p];
        acc += feat[s * D_H + t] * (dinv[s] * di);
    }
    if (bias) acc += bias[t];
    outf[node * D_H + t] = acc;
}

// ---- out = agg2 @ W2 + b2 ----
__global__ void out_kernel(const float* __restrict__ agg2, const float* __restrict__ W2,
                           const float* __restrict__ b2, float* __restrict__ out) {
    int idx = blockIdx.x * blockDim.x + threadIdx.x;   // over N*32 float4 groups
    if (idx >= N_NODES * (D_IN / 4)) return;
    int row = idx >> 5;
    int j4 = idx & 31;
    const float* ar = agg2 + row * D_H;
    float4 acc = ((const float4*)b2)[j4];
    #pragma unroll
    for (int c = 0; c < D_H; ++c) {
        float a = ar[c];
        float4 w = ((const float4*)(W2 + c * D_IN))[j4];
        acc.x += a * w.x; acc.y += a * w.y; acc.z += a * w.z; acc.w += a * w.w;
    }
    ((float4*)(out))[idx] = acc;
}

extern "C" void kernel_launch(void* const* d_in, const int* in_sizes, int n_in,
                              void* d_out, int out_size, void* d_ws, size_t ws_size,
                              hipStream_t stream) {
    const float* x  = (const float*)d_in[0];
    const int*   ei = (const int*)d_in[1];   // [2, E]: src then dst
    const float* W1 = (const float*)d_in[2];
    const float* b1 = (const float*)d_in[3];
    const float* W2 = (const float*)d_in[4];
    const float* b2 = (const float*)d_in[5];
    float* out = (float*)d_out;

    const int* src = ei;
    const int* dst = ei + N_EDGES;

    // ws carve (all 4-byte elems, 16B-aligned sections)
    char* base = (char*)d_ws;
    int*   degi     = (int*)base;                 base += ((N_NODES + 3) & ~3) * 4;
    int*   row_off  = (int*)base;                 base += ((N_NODES + 1 + 3) & ~3) * 4;
    int*   cursor   = (int*)base;                 base += ((N_NODES + 3) & ~3) * 4;
    int*   part     = (int*)base;                 base += SCAN_B * 4;
    int*   edge_src = (int*)base;                 base += N_EDGES * 4;
    float* dinv     = (float*)base;               base += ((N_NODES + 3) & ~3) * 4;
    float* h1       = (float*)base;               base += N_NODES * D_H * 4;
    float* z        = (float*)base;               base += N_NODES * D_H * 4;
    float* agg2     = (float*)base;               base += N_NODES * D_H * 4;

    hipMemsetAsync(degi, 0, N_NODES * sizeof(int), stream);

    deg_int_kernel<<<(N_EDGES + 255) / 256, 256, 0, stream>>>(dst, degi);
    dinv_kernel<<<(N_NODES + 255) / 256, 256, 0, stream>>>(degi, dinv);

    scan_partial<<<N_CHUNK, SCAN_B, 0, stream>>>(degi, part);
    scan_spine<<<1, SCAN_B, 0, stream>>>(part, row_off);
    scan_final<<<N_CHUNK, SCAN_B, 0, stream>>>(degi, part, row_off, cursor);
    fill_kernel<<<(N_EDGES + 255) / 256, 256, 0, stream>>>(src, dst, cursor, edge_src);

    h1_kernel<<<(N_NODES * D_H + 255) / 256, 256, 0, stream>>>(x, W1, h1);

    // encoder: z = Agg(h1) + b1
    gather_kernel<<<(N_NODES + 15) / 16, 256, 0, stream>>>(h1, row_off, edge_src, dinv, b1, z);
    // decoder: agg2 = Agg(z)
    gather_kernel<<<(N_NODES + 15) / 16, 256, 0, stream>>>(z, row_off, edge_src, dinv, nullptr, agg2);

    out_kernel<<<(N_NODES * 32 + 255) / 256, 256, 0, stream>>>(agg2, W2, b2, out);
}